// Round 9
// baseline (239.776 us; speedup 1.0000x reference)
//
#include <hip/hip_runtime.h>
#include <hip/hip_bf16.h>

static constexpr int NN = 50000;   // nodes
static constexpr int NE = 800000;  // edges
static constexpr int NG = 512;     // graphs
static constexpr int NB = 196;     // 196*256 >= NN
static constexpr int GEMM_BLOCKS = (NN + 63) / 64;    // 782
static constexpr int HB = 128;     // dedicated histogram blocks (round-2 proven config)
static_assert(NN % 4 == 0, "agg kernels assume exact 4-node blocks");

__device__ __forceinline__ float bfu(ushort u) {
    return __uint_as_float((unsigned)u << 16);
}
__device__ __forceinline__ ushort fbf(float f) {
    return __hip_bfloat16_raw(__float2bfloat16(f)).x;
}

// ---------------- utility ----------------

__global__ void zero_kernel(float* __restrict__ p, int n) {
    int i = blockIdx.x * blockDim.x + threadIdx.x;
    if (i < n) p[i] = 0.f;
}

// ---------------- GEMM body: X [NN,128] @ W [128,64] -> out bf16 ----------------
// 64 rows/block, LDS-staged X + K-chunked W (16 KB), 16x16 threads, 4x4 register tile.
// Inner loop: k-groups of 4 with ds_read_b128 only (8 LDS instrs / 64 FMAs).
template <int K>
__device__ __forceinline__ void gemm_body(const float* __restrict__ X,
                                          const float* __restrict__ W,
                                          ushort* __restrict__ out,
                                          int row0, float Xs[][68], float Ws[][64]) {
    int tx = threadIdx.x & 15, ty = threadIdx.x >> 4;
    float acc[4][4] = {};
    for (int kb = 0; kb < K; kb += 64) {
        __syncthreads();
        // stage W chunk: 64 k x 64 out = 1024 float4, coalesced
        for (int i = threadIdx.x; i < 1024; i += 256) {
            int kk = i >> 4, c4 = i & 15;
            *(float4*)&Ws[kk][c4 * 4] = *(const float4*)&W[(kb + kk) * 64 + c4 * 4];
        }
        for (int i = threadIdx.x; i < 1024; i += 256) {  // 64 rows x 16 float4
            int r = i >> 4, k4 = i & 15;
            int gr = row0 + r; if (gr >= NN) gr = NN - 1;
            float4 v = *(const float4*)(X + (long long)gr * K + kb + k4 * 4);
            *(float4*)&Xs[r][k4 * 4] = v;
        }
        __syncthreads();
#pragma unroll
        for (int k4 = 0; k4 < 16; ++k4) {
            float4 w0 = *(const float4*)&Ws[k4 * 4 + 0][tx * 4];
            float4 w1 = *(const float4*)&Ws[k4 * 4 + 1][tx * 4];
            float4 w2 = *(const float4*)&Ws[k4 * 4 + 2][tx * 4];
            float4 w3 = *(const float4*)&Ws[k4 * 4 + 3][tx * 4];
            float4 x0 = *(const float4*)&Xs[ty * 4 + 0][k4 * 4];
            float4 x1 = *(const float4*)&Xs[ty * 4 + 1][k4 * 4];
            float4 x2 = *(const float4*)&Xs[ty * 4 + 2][k4 * 4];
            float4 x3 = *(const float4*)&Xs[ty * 4 + 3][k4 * 4];
#define GCN_ROW(j, xv) \
            acc[j][0]=fmaf(xv.x,w0.x,acc[j][0]); acc[j][1]=fmaf(xv.x,w0.y,acc[j][1]); \
            acc[j][2]=fmaf(xv.x,w0.z,acc[j][2]); acc[j][3]=fmaf(xv.x,w0.w,acc[j][3]); \
            acc[j][0]=fmaf(xv.y,w1.x,acc[j][0]); acc[j][1]=fmaf(xv.y,w1.y,acc[j][1]); \
            acc[j][2]=fmaf(xv.y,w1.z,acc[j][2]); acc[j][3]=fmaf(xv.y,w1.w,acc[j][3]); \
            acc[j][0]=fmaf(xv.z,w2.x,acc[j][0]); acc[j][1]=fmaf(xv.z,w2.y,acc[j][1]); \
            acc[j][2]=fmaf(xv.z,w2.z,acc[j][2]); acc[j][3]=fmaf(xv.z,w2.w,acc[j][3]); \
            acc[j][0]=fmaf(xv.w,w3.x,acc[j][0]); acc[j][1]=fmaf(xv.w,w3.y,acc[j][1]); \
            acc[j][2]=fmaf(xv.w,w3.z,acc[j][2]); acc[j][3]=fmaf(xv.w,w3.w,acc[j][3]);
            GCN_ROW(0, x0)
            GCN_ROW(1, x1)
            GCN_ROW(2, x2)
            GCN_ROW(3, x3)
#undef GCN_ROW
        }
    }
#pragma unroll
    for (int j = 0; j < 4; ++j) {
        int r = row0 + ty * 4 + j;
        if (r < NN) {
            ushort4 sv;
            sv.x = fbf(acc[j][0]); sv.y = fbf(acc[j][1]);
            sv.z = fbf(acc[j][2]); sv.w = fbf(acc[j][3]);
            *(ushort4*)(out + (long long)r * 64 + tx * 4) = sv;
        }
    }
}

// ---------------- fused: role-split hist blocks || gemm blocks -------------------------
// Blocks [0,HB) grid-stride the full edge list issuing the atomic histogram (single
// table, simple loop — round-2 proven fastest config); blocks [HB, HB+GEMM_BLOCKS)
// run x @ W1. All 910 blocks co-resident (33.8 KB LDS -> 4 blocks/CU), so the
// atomic-throughput-bound stream overlaps the GEMM's LDS/VALU work.
__global__ __launch_bounds__(256) void hist_gemm_kernel(const int* __restrict__ dst,
                                                        const float* __restrict__ ew,
                                                        unsigned long long* __restrict__ h,
                                                        int* __restrict__ rank,
                                                        const float* __restrict__ X,
                                                        const float* __restrict__ W,
                                                        ushort* __restrict__ out) {
    __shared__ float Xs[64][68];      // 2-way conflicts only (free)
    __shared__ float Ws[64][64];      // K-chunk of W
    if (blockIdx.x < HB) {
        // one 64-bit atomic per edge: count in [40:64), sum(ew) fixed-point 2^-20 in [0:40)
        // returned old count = edge's rank within its dst group (free CSR fill counter)
        for (int e = blockIdx.x * 256 + threadIdx.x; e < NE; e += HB * 256) {
            int d = dst[e];
            unsigned int fx = __float2uint_rn(ew[e] * 1048576.0f);
            unsigned long long pack = (1ULL << 40) | (unsigned long long)fx;
            unsigned long long old = atomicAdd(&h[d], pack);
            rank[e] = (int)(old >> 40);
        }
        return;
    }
    gemm_body<128>(X, W, out, (blockIdx.x - HB) * 64, Xs, Ws);
}

// fused: dinv computation + per-block count reduction (scan phase A)
__global__ __launch_bounds__(256) void dinv_scanA_kernel(const unsigned long long* __restrict__ h,
                                                         float* __restrict__ dinv,
                                                         int* __restrict__ partial) {
    int i = blockIdx.x * 256 + threadIdx.x;
    int cnt = 0;
    if (i < NN) {
        unsigned long long v = h[i];
        cnt = (int)(v >> 40);
        float deg = (float)(v & ((1ULL << 40) - 1)) * (1.0f / 1048576.0f) + 1.0f;
        dinv[i] = 1.0f / sqrtf(deg);
    }
    __shared__ int wsum[4];
    int lane = threadIdx.x & 63, wid = threadIdx.x >> 6;
    int v = cnt;
#pragma unroll
    for (int off = 32; off > 0; off >>= 1) v += __shfl_down(v, (unsigned)off, 64);
    if (lane == 0) wsum[wid] = v;
    __syncthreads();
    if (threadIdx.x == 0) partial[blockIdx.x] = wsum[0] + wsum[1] + wsum[2] + wsum[3];
}

__device__ __forceinline__ int block_scan_inclusive(int v, int* wtot) {
    int lane = threadIdx.x & 63, wid = threadIdx.x >> 6;
    int inc = v;
#pragma unroll
    for (int off = 1; off < 64; off <<= 1) {
        int n = __shfl_up(inc, (unsigned)off, 64);
        if (lane >= off) inc += n;
    }
    if (lane == 63) wtot[wid] = inc;
    __syncthreads();
    int add = 0;
    for (int w = 0; w < wid; ++w) add += wtot[w];
    return inc + add;
}

// fused: per-block prefix of partials (196 L2-hot ints) + rowptr finalize + graph bounds
__global__ __launch_bounds__(256) void scanC_bounds_kernel(const unsigned long long* __restrict__ h,
                                                           const int* __restrict__ partial,
                                                           int* __restrict__ rowptr,
                                                           const int* __restrict__ batch,
                                                           int* __restrict__ gbeg,
                                                           int* __restrict__ gend) {
    __shared__ int wtot[4];
    __shared__ int poff_s;
    int t = threadIdx.x;
    if (t < 64) {   // wave 0: poff = sum partial[0..bid-1]
        int s = 0;
        for (int i = t; i < (int)blockIdx.x; i += 64) s += partial[i];
#pragma unroll
        for (int off = 32; off > 0; off >>= 1) s += __shfl_down(s, (unsigned)off, 64);
        if (t == 0) poff_s = s;
    }
    int i = blockIdx.x * 256 + t;
    int v = (i < NN) ? (int)(h[i] >> 40) : 0;
    int incl = block_scan_inclusive(v, wtot);   // internal __syncthreads makes poff_s visible
    if (i < NN) {
        rowptr[i + 1] = poff_s + incl;
        int g = batch[i];
        if (i == 0 || batch[i - 1] != g) gbeg[g] = i;
        if (i == NN - 1 || batch[i + 1] != g) gend[g] = i + 1;
    }
    if (i == 0) rowptr[0] = 0;
}

// Atomic-free scatter: pos = rowptr[d] + rank[e]; epack[pos] = (src, dinv[s]*ew)
__global__ __launch_bounds__(256) void scatter_kernel(const int* __restrict__ src,
                                                      const int* __restrict__ dst,
                                                      const float* __restrict__ ew,
                                                      const float* __restrict__ dinv,
                                                      const int* __restrict__ rowptr,
                                                      const int* __restrict__ rank,
                                                      int2* __restrict__ epack) {
    int e = blockIdx.x * blockDim.x + threadIdx.x;
    if (e >= NE) return;
    int s = src[e], d = dst[e];
    int pos = rowptr[d] + rank[e];
    float coef = dinv[s] * ew[e];
    epack[pos] = make_int2(s, __float_as_int(coef));
}

// ---------------- fused agg1 + ReLU + gemm2: per block, 4 nodes -----------------------
// Phase 1 (per wave = 1 node): h1[node,:] = relu(b1 + dinv^2*xw1[node,:] +
//   dinv * sum_j coef_j * xw1[src_j,:])  -- 8 lanes/edge x 8 ch/lane, kept in fp32.
// Phase 2: xw2[node,:] = h1[node,:] @ W2. W2 column (outch = lane) preloaded into 64
// VGPRs via coalesced one-time loads; h1 read back as 16 wave-uniform ds_read_b128.
// LDS-pipe ops in phase 2: 16/thread (was 128 scalar ds_read_b32) — the LDS issue
// pipe was the marginal cost of the fusion (r6: VALU 38%, HBM 10%, occ 71%).
// __syncthreads between phases: defensive vs compiler reordering of the exec-masked
// LDS write against the full-wave read (rule-18-style hazard); cost ~1 barrier/block.
__global__ __launch_bounds__(256) void agg_gemm_kernel(const ushort* __restrict__ xw,
                                                       const int* __restrict__ rowptr,
                                                       const int2* __restrict__ epack,
                                                       const float* __restrict__ dinv,
                                                       const float* __restrict__ bias,
                                                       const float* __restrict__ W2,
                                                       ushort* __restrict__ xw2) {
    __shared__ float h1s[4][64];    // per-wave h1 row
    int w = threadIdx.x >> 6;
    int node = blockIdx.x * 4 + w;           // always < NN (NN % 4 == 0)
    int lane = threadIdx.x & 63;
    // one-time: this thread's W2 column (outch = lane) into registers, coalesced per k
    float w2c[64];
#pragma unroll
    for (int k = 0; k < 64; ++k) w2c[k] = W2[k * 64 + lane];
    int e8 = lane >> 3;      // edge slot 0..7
    int l8 = lane & 7;       // channel group: ch 8*l8 .. 8*l8+7
    int beg = rowptr[node], end = rowptr[node + 1];
    float a0 = 0.f, a1 = 0.f, a2 = 0.f, a3 = 0.f;
    float a4 = 0.f, a5 = 0.f, a6 = 0.f, a7 = 0.f;
    for (int j = beg + e8; j < end; j += 8) {
        int2 p = epack[j];                                   // broadcast among 8 lanes
        uint4 v = *(const uint4*)(xw + p.x * 64 + l8 * 8);   // 16B = 8 bf16 channels
        float wt = __int_as_float(p.y);
        a0 = fmaf(wt, __uint_as_float(v.x << 16), a0);
        a1 = fmaf(wt, __uint_as_float(v.x & 0xffff0000u), a1);
        a2 = fmaf(wt, __uint_as_float(v.y << 16), a2);
        a3 = fmaf(wt, __uint_as_float(v.y & 0xffff0000u), a3);
        a4 = fmaf(wt, __uint_as_float(v.z << 16), a4);
        a5 = fmaf(wt, __uint_as_float(v.z & 0xffff0000u), a5);
        a6 = fmaf(wt, __uint_as_float(v.w << 16), a6);
        a7 = fmaf(wt, __uint_as_float(v.w & 0xffff0000u), a7);
    }
#define RED(x) x += __shfl_xor(x, 8); x += __shfl_xor(x, 16); x += __shfl_xor(x, 32);
    RED(a0) RED(a1) RED(a2) RED(a3) RED(a4) RED(a5) RED(a6) RED(a7)
#undef RED
    if (e8 == 0) {
        float di = dinv[node];
        float d2 = di * di;
        uint4 us = *(const uint4*)(xw + node * 64 + l8 * 8);
        float4 bv0 = *(const float4*)(bias + l8 * 8);
        float4 bv1 = *(const float4*)(bias + l8 * 8 + 4);
        float o0 = fmaf(di, a0, fmaf(d2, __uint_as_float(us.x << 16), bv0.x));
        float o1 = fmaf(di, a1, fmaf(d2, __uint_as_float(us.x & 0xffff0000u), bv0.y));
        float o2 = fmaf(di, a2, fmaf(d2, __uint_as_float(us.y << 16), bv0.z));
        float o3 = fmaf(di, a3, fmaf(d2, __uint_as_float(us.y & 0xffff0000u), bv0.w));
        float o4 = fmaf(di, a4, fmaf(d2, __uint_as_float(us.z << 16), bv1.x));
        float o5 = fmaf(di, a5, fmaf(d2, __uint_as_float(us.z & 0xffff0000u), bv1.y));
        float o6 = fmaf(di, a6, fmaf(d2, __uint_as_float(us.w << 16), bv1.z));
        float o7 = fmaf(di, a7, fmaf(d2, __uint_as_float(us.w & 0xffff0000u), bv1.w));
        *(float4*)&h1s[w][l8 * 8]     = make_float4(fmaxf(o0, 0.f), fmaxf(o1, 0.f),
                                                    fmaxf(o2, 0.f), fmaxf(o3, 0.f));
        *(float4*)&h1s[w][l8 * 8 + 4] = make_float4(fmaxf(o4, 0.f), fmaxf(o5, 0.f),
                                                    fmaxf(o6, 0.f), fmaxf(o7, 0.f));
    }
    __syncthreads();
    // phase 2: k ascending, identical accumulation order as before (bitexact).
    float acc = 0.f;
#pragma unroll
    for (int k4 = 0; k4 < 16; ++k4) {
        float4 hv = *(const float4*)&h1s[w][k4 * 4];     // wave-uniform b128 read
        acc = fmaf(hv.x, w2c[k4 * 4 + 0], acc);
        acc = fmaf(hv.y, w2c[k4 * 4 + 1], acc);
        acc = fmaf(hv.z, w2c[k4 * 4 + 2], acc);
        acc = fmaf(hv.w, w2c[k4 * 4 + 3], acc);
    }
    xw2[node * 64 + lane] = fbf(acc);
}

// ---------------- CSR aggregation (layer 2): 8 lanes/edge x 8 ch/lane ------------------
template <bool RELU>
__global__ __launch_bounds__(256) void agg_kernel(const ushort* __restrict__ xw,
                                                  const int* __restrict__ rowptr,
                                                  const int2* __restrict__ epack,
                                                  const float* __restrict__ dinv,
                                                  const float* __restrict__ bias,
                                                  ushort* __restrict__ out) {
    int node = blockIdx.x * 4 + (threadIdx.x >> 6);
    int lane = threadIdx.x & 63;
    int e8 = lane >> 3;
    int l8 = lane & 7;
    int beg = rowptr[node], end = rowptr[node + 1];
    float a0 = 0.f, a1 = 0.f, a2 = 0.f, a3 = 0.f;
    float a4 = 0.f, a5 = 0.f, a6 = 0.f, a7 = 0.f;
    for (int j = beg + e8; j < end; j += 8) {
        int2 p = epack[j];
        uint4 v = *(const uint4*)(xw + p.x * 64 + l8 * 8);
        float w = __int_as_float(p.y);
        a0 = fmaf(w, __uint_as_float(v.x << 16), a0);
        a1 = fmaf(w, __uint_as_float(v.x & 0xffff0000u), a1);
        a2 = fmaf(w, __uint_as_float(v.y << 16), a2);
        a3 = fmaf(w, __uint_as_float(v.y & 0xffff0000u), a3);
        a4 = fmaf(w, __uint_as_float(v.z << 16), a4);
        a5 = fmaf(w, __uint_as_float(v.z & 0xffff0000u), a5);
        a6 = fmaf(w, __uint_as_float(v.w << 16), a6);
        a7 = fmaf(w, __uint_as_float(v.w & 0xffff0000u), a7);
    }
#define RED(x) x += __shfl_xor(x, 8); x += __shfl_xor(x, 16); x += __shfl_xor(x, 32);
    RED(a0) RED(a1) RED(a2) RED(a3) RED(a4) RED(a5) RED(a6) RED(a7)
#undef RED
    if (e8 == 0) {
        float di = dinv[node];
        float d2 = di * di;
        uint4 us = *(const uint4*)(xw + node * 64 + l8 * 8);
        float4 bv0 = *(const float4*)(bias + l8 * 8);
        float4 bv1 = *(const float4*)(bias + l8 * 8 + 4);
        float o0 = fmaf(di, a0, fmaf(d2, __uint_as_float(us.x << 16), bv0.x));
        float o1 = fmaf(di, a1, fmaf(d2, __uint_as_float(us.x & 0xffff0000u), bv0.y));
        float o2 = fmaf(di, a2, fmaf(d2, __uint_as_float(us.y << 16), bv0.z));
        float o3 = fmaf(di, a3, fmaf(d2, __uint_as_float(us.y & 0xffff0000u), bv0.w));
        float o4 = fmaf(di, a4, fmaf(d2, __uint_as_float(us.z << 16), bv1.x));
        float o5 = fmaf(di, a5, fmaf(d2, __uint_as_float(us.z & 0xffff0000u), bv1.y));
        float o6 = fmaf(di, a6, fmaf(d2, __uint_as_float(us.w << 16), bv1.z));
        float o7 = fmaf(di, a7, fmaf(d2, __uint_as_float(us.w & 0xffff0000u), bv1.w));
        if (RELU) {
            o0 = fmaxf(o0, 0.f); o1 = fmaxf(o1, 0.f); o2 = fmaxf(o2, 0.f); o3 = fmaxf(o3, 0.f);
            o4 = fmaxf(o4, 0.f); o5 = fmaxf(o5, 0.f); o6 = fmaxf(o6, 0.f); o7 = fmaxf(o7, 0.f);
        }
        uint4 sv;
        sv.x = (unsigned)fbf(o0) | ((unsigned)fbf(o1) << 16);
        sv.y = (unsigned)fbf(o2) | ((unsigned)fbf(o3) << 16);
        sv.z = (unsigned)fbf(o4) | ((unsigned)fbf(o5) << 16);
        sv.w = (unsigned)fbf(o6) | ((unsigned)fbf(o7) << 16);
        *(uint4*)(out + node * 64 + l8 * 8) = sv;
    }
}

// ---------------- fused mean-pool + MLP head: 4 waves per graph (h is bf16) -----------
__global__ __launch_bounds__(256) void poolhead_kernel(const ushort* __restrict__ h,
                                                       const int* __restrict__ gbeg,
                                                       const int* __restrict__ gend,
                                                       const float* __restrict__ LW1,
                                                       const float* __restrict__ Lb1,
                                                       const float* __restrict__ LW2,
                                                       const float* __restrict__ Lb2,
                                                       float* __restrict__ out) {
    __shared__ float pp[4][64];
    __shared__ float p[64];
    __shared__ float t1[32];
    int g = blockIdx.x, t = threadIdx.x;
    int lane = t & 63, wid = t >> 6;
    int b = gbeg[g], e = gend[g];
    float acc = 0.f;
    for (int i = b + wid; i < e; i += 4) acc += bfu(h[i * 64 + lane]);
    pp[wid][lane] = acc;
    __syncthreads();
    if (t < 64) {
        float s = pp[0][t] + pp[1][t] + pp[2][t] + pp[3][t];
        p[t] = s / fmaxf((float)(e - b), 1.0f);
    }
    __syncthreads();
    if (t < 32) {
        float a = Lb1[t];
#pragma unroll
        for (int k = 0; k < 64; ++k) a = fmaf(p[k], LW1[k * 32 + t], a);
        t1[t] = a;
    }
    __syncthreads();
    if (t < 10) {
        float a = Lb2[t];
#pragma unroll
        for (int j = 0; j < 32; ++j) a = fmaf(t1[j], LW2[j * 10 + t], a);
        out[g * 10 + t] = a;
    }
}

// ---------------- launch ----------------

extern "C" void kernel_launch(void* const* d_in, const int* in_sizes, int n_in,
                              void* d_out, int out_size, void* d_ws, size_t ws_size,
                              hipStream_t stream) {
    const float* x     = (const float*)d_in[0];
    const int*   ei    = (const int*)d_in[1];   // [2, NE]
    const float* ew    = (const float*)d_in[2];
    const int*   batch = (const int*)d_in[3];
    const float* W1    = (const float*)d_in[4];
    const float* b1    = (const float*)d_in[5];
    const float* W2    = (const float*)d_in[6];
    const float* b2    = (const float*)d_in[7];
    const float* LW1   = (const float*)d_in[8];
    const float* Lb1   = (const float*)d_in[9];
    const float* LW2   = (const float*)d_in[10];
    const float* Lb2   = (const float*)d_in[11];

    const int* src = ei;
    const int* dst = ei + NE;

    // workspace layout (4-byte units)
    float* ws = (float*)d_ws;
    unsigned long long* h64 = (unsigned long long*)ws;  // [NN] ull: 0 .. 100096
    int*   gbeg   = (int*)(ws + 100096);       // [NG] -> 100608
    int*   gend   = (int*)(ws + 100608);       // [NG] -> 101120  (zero range ends here)
    float* dinv   = ws + 101120;               // [NN]   -> 151168
    int*   rowptr = (int*)(ws + 151168);       // [NN+1] -> 201248 (padded)
    int*   partial= (int*)(ws + 201248);       // [NB]   -> 201504 (even -> int2-aligned)
    int2*  epack  = (int2*)(ws + 201504);      // [NE]   -> 1801504
    ushort* xwA   = (ushort*)(ws + 1801504);   // [NN*64] bf16: xw1; later reused as h2 -> 3401504
    ushort* xwB   = (ushort*)(ws + 3401504);   // [NN*64] bf16: xw2 -> 5001504
    int*   rank   = (int*)(ws + 5001504);      // [NE] -> 5801504
    ushort* h2    = xwA;                       // xw1 dead once agg_gemm completes
    // total 5801504 floats = 23.2 MB

    zero_kernel<<<(101120 + 255) / 256, 256, 0, stream>>>(ws, 101120);

    // role-split: blocks [0,HB) = atomic histogram (grid-stride), rest = x @ W1 GEMM
    hist_gemm_kernel<<<HB + GEMM_BLOCKS, 256, 0, stream>>>(dst, ew, h64, rank, x, W1, xwA);
    dinv_scanA_kernel<<<NB, 256, 0, stream>>>(h64, dinv, partial);
    scanC_bounds_kernel<<<NB, 256, 0, stream>>>(h64, partial, rowptr, batch, gbeg, gend);
    scatter_kernel<<<(NE + 255) / 256, 256, 0, stream>>>(src, dst, ew, dinv, rowptr,
                                                         rank, epack);

    // ---- layer 1 aggregation + ReLU + layer-2 GEMM fused ----
    agg_gemm_kernel<<<NN / 4, 256, 0, stream>>>(xwA, rowptr, epack, dinv, b1, W2, xwB);

    // ---- layer 2 aggregation ----
    agg_kernel<false><<<NN / 4, 256, 0, stream>>>(xwB, rowptr, epack, dinv, b2, h2);

    // ---- pool + head ----
    poolhead_kernel<<<NG, 256, 0, stream>>>(h2, gbeg, gend, LW1, Lb1, LW2, Lb2, (float*)d_out);
}

// Round 10
// 230.366 us; speedup vs baseline: 1.0408x; 1.0408x over previous
//
#include <hip/hip_runtime.h>
#include <hip/hip_bf16.h>

static constexpr int NN = 50000;   // nodes
static constexpr int NE = 800000;  // edges
static constexpr int NG = 512;     // graphs
static constexpr int NB = 196;     // 196*256 >= NN
static constexpr int GEMM_BLOCKS = (NN + 63) / 64;    // 782
static constexpr int HB = 128;     // dedicated histogram blocks (round-2 proven config)
static_assert(NN % 4 == 0, "agg kernels assume exact 4-node blocks");

__device__ __forceinline__ float bfu(ushort u) {
    return __uint_as_float((unsigned)u << 16);
}
__device__ __forceinline__ ushort fbf(float f) {
    return __hip_bfloat16_raw(__float2bfloat16(f)).x;
}

// ---------------- utility ----------------

__global__ void zero_kernel(float* __restrict__ p, int n) {
    int i = blockIdx.x * blockDim.x + threadIdx.x;
    if (i < n) p[i] = 0.f;
}

// ---------------- GEMM body: X [NN,128] @ W [128,64] -> out bf16 ----------------
// 64 rows/block, LDS-staged X + K-chunked W (16 KB), 16x16 threads, 4x4 register tile.
// Inner loop: k-groups of 4 with ds_read_b128 only (8 LDS instrs / 64 FMAs).
template <int K>
__device__ __forceinline__ void gemm_body(const float* __restrict__ X,
                                          const float* __restrict__ W,
                                          ushort* __restrict__ out,
                                          int row0, float Xs[][68], float Ws[][64]) {
    int tx = threadIdx.x & 15, ty = threadIdx.x >> 4;
    float acc[4][4] = {};
    for (int kb = 0; kb < K; kb += 64) {
        __syncthreads();
        // stage W chunk: 64 k x 64 out = 1024 float4, coalesced
        for (int i = threadIdx.x; i < 1024; i += 256) {
            int kk = i >> 4, c4 = i & 15;
            *(float4*)&Ws[kk][c4 * 4] = *(const float4*)&W[(kb + kk) * 64 + c4 * 4];
        }
        for (int i = threadIdx.x; i < 1024; i += 256) {  // 64 rows x 16 float4
            int r = i >> 4, k4 = i & 15;
            int gr = row0 + r; if (gr >= NN) gr = NN - 1;
            float4 v = *(const float4*)(X + (long long)gr * K + kb + k4 * 4);
            *(float4*)&Xs[r][k4 * 4] = v;
        }
        __syncthreads();
#pragma unroll
        for (int k4 = 0; k4 < 16; ++k4) {
            float4 w0 = *(const float4*)&Ws[k4 * 4 + 0][tx * 4];
            float4 w1 = *(const float4*)&Ws[k4 * 4 + 1][tx * 4];
            float4 w2 = *(const float4*)&Ws[k4 * 4 + 2][tx * 4];
            float4 w3 = *(const float4*)&Ws[k4 * 4 + 3][tx * 4];
            float4 x0 = *(const float4*)&Xs[ty * 4 + 0][k4 * 4];
            float4 x1 = *(const float4*)&Xs[ty * 4 + 1][k4 * 4];
            float4 x2 = *(const float4*)&Xs[ty * 4 + 2][k4 * 4];
            float4 x3 = *(const float4*)&Xs[ty * 4 + 3][k4 * 4];
#define GCN_ROW(j, xv) \
            acc[j][0]=fmaf(xv.x,w0.x,acc[j][0]); acc[j][1]=fmaf(xv.x,w0.y,acc[j][1]); \
            acc[j][2]=fmaf(xv.x,w0.z,acc[j][2]); acc[j][3]=fmaf(xv.x,w0.w,acc[j][3]); \
            acc[j][0]=fmaf(xv.y,w1.x,acc[j][0]); acc[j][1]=fmaf(xv.y,w1.y,acc[j][1]); \
            acc[j][2]=fmaf(xv.y,w1.z,acc[j][2]); acc[j][3]=fmaf(xv.y,w1.w,acc[j][3]); \
            acc[j][0]=fmaf(xv.z,w2.x,acc[j][0]); acc[j][1]=fmaf(xv.z,w2.y,acc[j][1]); \
            acc[j][2]=fmaf(xv.z,w2.z,acc[j][2]); acc[j][3]=fmaf(xv.z,w2.w,acc[j][3]); \
            acc[j][0]=fmaf(xv.w,w3.x,acc[j][0]); acc[j][1]=fmaf(xv.w,w3.y,acc[j][1]); \
            acc[j][2]=fmaf(xv.w,w3.z,acc[j][2]); acc[j][3]=fmaf(xv.w,w3.w,acc[j][3]);
            GCN_ROW(0, x0)
            GCN_ROW(1, x1)
            GCN_ROW(2, x2)
            GCN_ROW(3, x3)
#undef GCN_ROW
        }
    }
#pragma unroll
    for (int j = 0; j < 4; ++j) {
        int r = row0 + ty * 4 + j;
        if (r < NN) {
            ushort4 sv;
            sv.x = fbf(acc[j][0]); sv.y = fbf(acc[j][1]);
            sv.z = fbf(acc[j][2]); sv.w = fbf(acc[j][3]);
            *(ushort4*)(out + (long long)r * 64 + tx * 4) = sv;
        }
    }
}

// ---------------- fused: role-split hist blocks || gemm blocks -------------------------
// Blocks [0,HB) grid-stride the full edge list issuing the atomic histogram (single
// table, simple loop — round-2 proven fastest config); blocks [HB, HB+GEMM_BLOCKS)
// run x @ W1. All 910 blocks co-resident (33.8 KB LDS -> 4 blocks/CU), so the
// atomic-throughput-bound stream overlaps the GEMM's LDS/VALU work.
__global__ __launch_bounds__(256) void hist_gemm_kernel(const int* __restrict__ dst,
                                                        const float* __restrict__ ew,
                                                        unsigned long long* __restrict__ h,
                                                        int* __restrict__ rank,
                                                        const float* __restrict__ X,
                                                        const float* __restrict__ W,
                                                        ushort* __restrict__ out) {
    __shared__ float Xs[64][68];      // 2-way conflicts only (free)
    __shared__ float Ws[64][64];      // K-chunk of W
    if (blockIdx.x < HB) {
        // one 64-bit atomic per edge: count in [40:64), sum(ew) fixed-point 2^-20 in [0:40)
        // returned old count = edge's rank within its dst group (free CSR fill counter)
        for (int e = blockIdx.x * 256 + threadIdx.x; e < NE; e += HB * 256) {
            int d = dst[e];
            unsigned int fx = __float2uint_rn(ew[e] * 1048576.0f);
            unsigned long long pack = (1ULL << 40) | (unsigned long long)fx;
            unsigned long long old = atomicAdd(&h[d], pack);
            rank[e] = (int)(old >> 40);
        }
        return;
    }
    gemm_body<128>(X, W, out, (blockIdx.x - HB) * 64, Xs, Ws);
}

// fused: dinv computation + per-block count reduction (scan phase A)
__global__ __launch_bounds__(256) void dinv_scanA_kernel(const unsigned long long* __restrict__ h,
                                                         float* __restrict__ dinv,
                                                         int* __restrict__ partial) {
    int i = blockIdx.x * 256 + threadIdx.x;
    int cnt = 0;
    if (i < NN) {
        unsigned long long v = h[i];
        cnt = (int)(v >> 40);
        float deg = (float)(v & ((1ULL << 40) - 1)) * (1.0f / 1048576.0f) + 1.0f;
        dinv[i] = 1.0f / sqrtf(deg);
    }
    __shared__ int wsum[4];
    int lane = threadIdx.x & 63, wid = threadIdx.x >> 6;
    int v = cnt;
#pragma unroll
    for (int off = 32; off > 0; off >>= 1) v += __shfl_down(v, (unsigned)off, 64);
    if (lane == 0) wsum[wid] = v;
    __syncthreads();
    if (threadIdx.x == 0) partial[blockIdx.x] = wsum[0] + wsum[1] + wsum[2] + wsum[3];
}

__device__ __forceinline__ int block_scan_inclusive(int v, int* wtot) {
    int lane = threadIdx.x & 63, wid = threadIdx.x >> 6;
    int inc = v;
#pragma unroll
    for (int off = 1; off < 64; off <<= 1) {
        int n = __shfl_up(inc, (unsigned)off, 64);
        if (lane >= off) inc += n;
    }
    if (lane == 63) wtot[wid] = inc;
    __syncthreads();
    int add = 0;
    for (int w = 0; w < wid; ++w) add += wtot[w];
    return inc + add;
}

// fused: per-block prefix of partials (196 L2-hot ints) + rowptr finalize + graph bounds
__global__ __launch_bounds__(256) void scanC_bounds_kernel(const unsigned long long* __restrict__ h,
                                                           const int* __restrict__ partial,
                                                           int* __restrict__ rowptr,
                                                           const int* __restrict__ batch,
                                                           int* __restrict__ gbeg,
                                                           int* __restrict__ gend) {
    __shared__ int wtot[4];
    __shared__ int poff_s;
    int t = threadIdx.x;
    if (t < 64) {   // wave 0: poff = sum partial[0..bid-1]
        int s = 0;
        for (int i = t; i < (int)blockIdx.x; i += 64) s += partial[i];
#pragma unroll
        for (int off = 32; off > 0; off >>= 1) s += __shfl_down(s, (unsigned)off, 64);
        if (t == 0) poff_s = s;
    }
    int i = blockIdx.x * 256 + t;
    int v = (i < NN) ? (int)(h[i] >> 40) : 0;
    int incl = block_scan_inclusive(v, wtot);   // internal __syncthreads makes poff_s visible
    if (i < NN) {
        rowptr[i + 1] = poff_s + incl;
        int g = batch[i];
        if (i == 0 || batch[i - 1] != g) gbeg[g] = i;
        if (i == NN - 1 || batch[i + 1] != g) gend[g] = i + 1;
    }
    if (i == 0) rowptr[0] = 0;
}

// Atomic-free scatter: pos = rowptr[d] + rank[e]; epack[pos] = (src, dinv[s]*ew)
__global__ __launch_bounds__(256) void scatter_kernel(const int* __restrict__ src,
                                                      const int* __restrict__ dst,
                                                      const float* __restrict__ ew,
                                                      const float* __restrict__ dinv,
                                                      const int* __restrict__ rowptr,
                                                      const int* __restrict__ rank,
                                                      int2* __restrict__ epack) {
    int e = blockIdx.x * blockDim.x + threadIdx.x;
    if (e >= NE) return;
    int s = src[e], d = dst[e];
    int pos = rowptr[d] + rank[e];
    float coef = dinv[s] * ew[e];
    epack[pos] = make_int2(s, __float_as_int(coef));
}

// ---------------- fused agg1 + ReLU + gemm2: per block, 4 nodes -----------------------
// Phase 1 (per wave = 1 node): h1[node,:] = relu(b1 + dinv^2*xw1[node,:] +
//   dinv * sum_j coef_j * xw1[src_j,:])  -- 8 lanes/edge x 8 ch/lane, kept in fp32.
// Phase 2: xw2[node,:] = h1[node,:] @ W2, reading W2 DIRECTLY from global in the
// unrolled k-loop: each load is lane-contiguous (perfectly coalesced) and the 16 KB
// W2 is L1-resident (every wave on the CU reads the same matrix). No register array
// (r9's w2c[64] spilled to scratch: VGPR=52 < 64 needed, occ 71->38%, +10 us), no
// LDS W2 stage (r6's 128 scalar ds_read_b32/thread saturated the LDS issue pipe).
// h1 read back as 16 wave-uniform ds_read_b128; LDS total 1 KB.
__global__ __launch_bounds__(256) void agg_gemm_kernel(const ushort* __restrict__ xw,
                                                       const int* __restrict__ rowptr,
                                                       const int2* __restrict__ epack,
                                                       const float* __restrict__ dinv,
                                                       const float* __restrict__ bias,
                                                       const float* __restrict__ W2,
                                                       ushort* __restrict__ xw2) {
    __shared__ float h1s[4][64];    // per-wave h1 row
    int w = threadIdx.x >> 6;
    int node = blockIdx.x * 4 + w;           // always < NN (NN % 4 == 0)
    int lane = threadIdx.x & 63;
    int e8 = lane >> 3;      // edge slot 0..7
    int l8 = lane & 7;       // channel group: ch 8*l8 .. 8*l8+7
    int beg = rowptr[node], end = rowptr[node + 1];
    float a0 = 0.f, a1 = 0.f, a2 = 0.f, a3 = 0.f;
    float a4 = 0.f, a5 = 0.f, a6 = 0.f, a7 = 0.f;
    for (int j = beg + e8; j < end; j += 8) {
        int2 p = epack[j];                                   // broadcast among 8 lanes
        uint4 v = *(const uint4*)(xw + p.x * 64 + l8 * 8);   // 16B = 8 bf16 channels
        float wt = __int_as_float(p.y);
        a0 = fmaf(wt, __uint_as_float(v.x << 16), a0);
        a1 = fmaf(wt, __uint_as_float(v.x & 0xffff0000u), a1);
        a2 = fmaf(wt, __uint_as_float(v.y << 16), a2);
        a3 = fmaf(wt, __uint_as_float(v.y & 0xffff0000u), a3);
        a4 = fmaf(wt, __uint_as_float(v.z << 16), a4);
        a5 = fmaf(wt, __uint_as_float(v.z & 0xffff0000u), a5);
        a6 = fmaf(wt, __uint_as_float(v.w << 16), a6);
        a7 = fmaf(wt, __uint_as_float(v.w & 0xffff0000u), a7);
    }
#define RED(x) x += __shfl_xor(x, 8); x += __shfl_xor(x, 16); x += __shfl_xor(x, 32);
    RED(a0) RED(a1) RED(a2) RED(a3) RED(a4) RED(a5) RED(a6) RED(a7)
#undef RED
    if (e8 == 0) {
        float di = dinv[node];
        float d2 = di * di;
        uint4 us = *(const uint4*)(xw + node * 64 + l8 * 8);
        float4 bv0 = *(const float4*)(bias + l8 * 8);
        float4 bv1 = *(const float4*)(bias + l8 * 8 + 4);
        float o0 = fmaf(di, a0, fmaf(d2, __uint_as_float(us.x << 16), bv0.x));
        float o1 = fmaf(di, a1, fmaf(d2, __uint_as_float(us.x & 0xffff0000u), bv0.y));
        float o2 = fmaf(di, a2, fmaf(d2, __uint_as_float(us.y << 16), bv0.z));
        float o3 = fmaf(di, a3, fmaf(d2, __uint_as_float(us.y & 0xffff0000u), bv0.w));
        float o4 = fmaf(di, a4, fmaf(d2, __uint_as_float(us.z << 16), bv1.x));
        float o5 = fmaf(di, a5, fmaf(d2, __uint_as_float(us.z & 0xffff0000u), bv1.y));
        float o6 = fmaf(di, a6, fmaf(d2, __uint_as_float(us.w << 16), bv1.z));
        float o7 = fmaf(di, a7, fmaf(d2, __uint_as_float(us.w & 0xffff0000u), bv1.w));
        *(float4*)&h1s[w][l8 * 8]     = make_float4(fmaxf(o0, 0.f), fmaxf(o1, 0.f),
                                                    fmaxf(o2, 0.f), fmaxf(o3, 0.f));
        *(float4*)&h1s[w][l8 * 8 + 4] = make_float4(fmaxf(o4, 0.f), fmaxf(o5, 0.f),
                                                    fmaxf(o6, 0.f), fmaxf(o7, 0.f));
    }
    __syncthreads();
    // phase 2: k ascending, identical accumulation order as before (bitexact).
    const float* W2l = W2 + lane;   // this thread's output-channel column
    float acc = 0.f;
#pragma unroll
    for (int k4 = 0; k4 < 16; ++k4) {
        float4 hv = *(const float4*)&h1s[w][k4 * 4];     // wave-uniform b128 read
        acc = fmaf(hv.x, W2l[(k4 * 4 + 0) * 64], acc);
        acc = fmaf(hv.y, W2l[(k4 * 4 + 1) * 64], acc);
        acc = fmaf(hv.z, W2l[(k4 * 4 + 2) * 64], acc);
        acc = fmaf(hv.w, W2l[(k4 * 4 + 3) * 64], acc);
    }
    xw2[node * 64 + lane] = fbf(acc);
}

// ---------------- CSR aggregation (layer 2): 8 lanes/edge x 8 ch/lane ------------------
template <bool RELU>
__global__ __launch_bounds__(256) void agg_kernel(const ushort* __restrict__ xw,
                                                  const int* __restrict__ rowptr,
                                                  const int2* __restrict__ epack,
                                                  const float* __restrict__ dinv,
                                                  const float* __restrict__ bias,
                                                  ushort* __restrict__ out) {
    int node = blockIdx.x * 4 + (threadIdx.x >> 6);
    int lane = threadIdx.x & 63;
    int e8 = lane >> 3;
    int l8 = lane & 7;
    int beg = rowptr[node], end = rowptr[node + 1];
    float a0 = 0.f, a1 = 0.f, a2 = 0.f, a3 = 0.f;
    float a4 = 0.f, a5 = 0.f, a6 = 0.f, a7 = 0.f;
    for (int j = beg + e8; j < end; j += 8) {
        int2 p = epack[j];
        uint4 v = *(const uint4*)(xw + p.x * 64 + l8 * 8);
        float w = __int_as_float(p.y);
        a0 = fmaf(w, __uint_as_float(v.x << 16), a0);
        a1 = fmaf(w, __uint_as_float(v.x & 0xffff0000u), a1);
        a2 = fmaf(w, __uint_as_float(v.y << 16), a2);
        a3 = fmaf(w, __uint_as_float(v.y & 0xffff0000u), a3);
        a4 = fmaf(w, __uint_as_float(v.z << 16), a4);
        a5 = fmaf(w, __uint_as_float(v.z & 0xffff0000u), a5);
        a6 = fmaf(w, __uint_as_float(v.w << 16), a6);
        a7 = fmaf(w, __uint_as_float(v.w & 0xffff0000u), a7);
    }
#define RED(x) x += __shfl_xor(x, 8); x += __shfl_xor(x, 16); x += __shfl_xor(x, 32);
    RED(a0) RED(a1) RED(a2) RED(a3) RED(a4) RED(a5) RED(a6) RED(a7)
#undef RED
    if (e8 == 0) {
        float di = dinv[node];
        float d2 = di * di;
        uint4 us = *(const uint4*)(xw + node * 64 + l8 * 8);
        float4 bv0 = *(const float4*)(bias + l8 * 8);
        float4 bv1 = *(const float4*)(bias + l8 * 8 + 4);
        float o0 = fmaf(di, a0, fmaf(d2, __uint_as_float(us.x << 16), bv0.x));
        float o1 = fmaf(di, a1, fmaf(d2, __uint_as_float(us.x & 0xffff0000u), bv0.y));
        float o2 = fmaf(di, a2, fmaf(d2, __uint_as_float(us.y << 16), bv0.z));
        float o3 = fmaf(di, a3, fmaf(d2, __uint_as_float(us.y & 0xffff0000u), bv0.w));
        float o4 = fmaf(di, a4, fmaf(d2, __uint_as_float(us.z << 16), bv1.x));
        float o5 = fmaf(di, a5, fmaf(d2, __uint_as_float(us.z & 0xffff0000u), bv1.y));
        float o6 = fmaf(di, a6, fmaf(d2, __uint_as_float(us.w << 16), bv1.z));
        float o7 = fmaf(di, a7, fmaf(d2, __uint_as_float(us.w & 0xffff0000u), bv1.w));
        if (RELU) {
            o0 = fmaxf(o0, 0.f); o1 = fmaxf(o1, 0.f); o2 = fmaxf(o2, 0.f); o3 = fmaxf(o3, 0.f);
            o4 = fmaxf(o4, 0.f); o5 = fmaxf(o5, 0.f); o6 = fmaxf(o6, 0.f); o7 = fmaxf(o7, 0.f);
        }
        uint4 sv;
        sv.x = (unsigned)fbf(o0) | ((unsigned)fbf(o1) << 16);
        sv.y = (unsigned)fbf(o2) | ((unsigned)fbf(o3) << 16);
        sv.z = (unsigned)fbf(o4) | ((unsigned)fbf(o5) << 16);
        sv.w = (unsigned)fbf(o6) | ((unsigned)fbf(o7) << 16);
        *(uint4*)(out + node * 64 + l8 * 8) = sv;
    }
}

// ---------------- fused mean-pool + MLP head: 4 waves per graph (h is bf16) -----------
__global__ __launch_bounds__(256) void poolhead_kernel(const ushort* __restrict__ h,
                                                       const int* __restrict__ gbeg,
                                                       const int* __restrict__ gend,
                                                       const float* __restrict__ LW1,
                                                       const float* __restrict__ Lb1,
                                                       const float* __restrict__ LW2,
                                                       const float* __restrict__ Lb2,
                                                       float* __restrict__ out) {
    __shared__ float pp[4][64];
    __shared__ float p[64];
    __shared__ float t1[32];
    int g = blockIdx.x, t = threadIdx.x;
    int lane = t & 63, wid = t >> 6;
    int b = gbeg[g], e = gend[g];
    float acc = 0.f;
    for (int i = b + wid; i < e; i += 4) acc += bfu(h[i * 64 + lane]);
    pp[wid][lane] = acc;
    __syncthreads();
    if (t < 64) {
        float s = pp[0][t] + pp[1][t] + pp[2][t] + pp[3][t];
        p[t] = s / fmaxf((float)(e - b), 1.0f);
    }
    __syncthreads();
    if (t < 32) {
        float a = Lb1[t];
#pragma unroll
        for (int k = 0; k < 64; ++k) a = fmaf(p[k], LW1[k * 32 + t], a);
        t1[t] = a;
    }
    __syncthreads();
    if (t < 10) {
        float a = Lb2[t];
#pragma unroll
        for (int j = 0; j < 32; ++j) a = fmaf(t1[j], LW2[j * 10 + t], a);
        out[g * 10 + t] = a;
    }
}

// ---------------- launch ----------------

extern "C" void kernel_launch(void* const* d_in, const int* in_sizes, int n_in,
                              void* d_out, int out_size, void* d_ws, size_t ws_size,
                              hipStream_t stream) {
    const float* x     = (const float*)d_in[0];
    const int*   ei    = (const int*)d_in[1];   // [2, NE]
    const float* ew    = (const float*)d_in[2];
    const int*   batch = (const int*)d_in[3];
    const float* W1    = (const float*)d_in[4];
    const float* b1    = (const float*)d_in[5];
    const float* W2    = (const float*)d_in[6];
    const float* b2    = (const float*)d_in[7];
    const float* LW1   = (const float*)d_in[8];
    const float* Lb1   = (const float*)d_in[9];
    const float* LW2   = (const float*)d_in[10];
    const float* Lb2   = (const float*)d_in[11];

    const int* src = ei;
    const int* dst = ei + NE;

    // workspace layout (4-byte units)
    float* ws = (float*)d_ws;
    unsigned long long* h64 = (unsigned long long*)ws;  // [NN] ull: 0 .. 100096
    int*   gbeg   = (int*)(ws + 100096);       // [NG] -> 100608
    int*   gend   = (int*)(ws + 100608);       // [NG] -> 101120  (zero range ends here)
    float* dinv   = ws + 101120;               // [NN]   -> 151168
    int*   rowptr = (int*)(ws + 151168);       // [NN+1] -> 201248 (padded)
    int*   partial= (int*)(ws + 201248);       // [NB]   -> 201504 (even -> int2-aligned)
    int2*  epack  = (int2*)(ws + 201504);      // [NE]   -> 1801504
    ushort* xwA   = (ushort*)(ws + 1801504);   // [NN*64] bf16: xw1; later reused as h2 -> 3401504
    ushort* xwB   = (ushort*)(ws + 3401504);   // [NN*64] bf16: xw2 -> 5001504
    int*   rank   = (int*)(ws + 5001504);      // [NE] -> 5801504
    ushort* h2    = xwA;                       // xw1 dead once agg_gemm completes
    // total 5801504 floats = 23.2 MB

    zero_kernel<<<(101120 + 255) / 256, 256, 0, stream>>>(ws, 101120);

    // role-split: blocks [0,HB) = atomic histogram (grid-stride), rest = x @ W1 GEMM
    hist_gemm_kernel<<<HB + GEMM_BLOCKS, 256, 0, stream>>>(dst, ew, h64, rank, x, W1, xwA);
    dinv_scanA_kernel<<<NB, 256, 0, stream>>>(h64, dinv, partial);
    scanC_bounds_kernel<<<NB, 256, 0, stream>>>(h64, partial, rowptr, batch, gbeg, gend);
    scatter_kernel<<<(NE + 255) / 256, 256, 0, stream>>>(src, dst, ew, dinv, rowptr,
                                                         rank, epack);

    // ---- layer 1 aggregation + ReLU + layer-2 GEMM fused ----
    agg_gemm_kernel<<<NN / 4, 256, 0, stream>>>(xwA, rowptr, epack, dinv, b1, W2, xwB);

    // ---- layer 2 aggregation ----
    agg_kernel<false><<<NN / 4, 256, 0, stream>>>(xwB, rowptr, epack, dinv, b2, h2);

    // ---- pool + head ----
    poolhead_kernel<<<NG, 256, 0, stream>>>(h2, gbeg, gend, LW1, Lb1, LW2, Lb2, (float*)d_out);
}

// Round 11
// 228.940 us; speedup vs baseline: 1.0473x; 1.0062x over previous
//
#include <hip/hip_runtime.h>
#include <hip/hip_bf16.h>

static constexpr int NN = 50000;   // nodes
static constexpr int NE = 800000;  // edges
static constexpr int NG = 512;     // graphs
static constexpr int NB = 196;     // 196*256 >= NN
static constexpr int GEMM_BLOCKS = (NN + 63) / 64;    // 782
static constexpr int HB = 128;     // dedicated histogram blocks (round-2 proven config)
static_assert(NN % 16 == 0, "agg_gemm assumes exact 16-node blocks");
static_assert(NN % 4 == 0, "agg kernels assume exact 4-node blocks");

__device__ __forceinline__ float bfu(ushort u) {
    return __uint_as_float((unsigned)u << 16);
}
__device__ __forceinline__ ushort fbf(float f) {
    return __hip_bfloat16_raw(__float2bfloat16(f)).x;
}

// ---------------- utility ----------------

__global__ void zero_kernel(float* __restrict__ p, int n) {
    int i = blockIdx.x * blockDim.x + threadIdx.x;
    if (i < n) p[i] = 0.f;
}

// ---------------- GEMM body: X [NN,128] @ W [128,64] -> out bf16 ----------------
// 64 rows/block, LDS-staged X + K-chunked W (16 KB), 16x16 threads, 4x4 register tile.
// Inner loop: k-groups of 4 with ds_read_b128 only (8 LDS instrs / 64 FMAs).
template <int K>
__device__ __forceinline__ void gemm_body(const float* __restrict__ X,
                                          const float* __restrict__ W,
                                          ushort* __restrict__ out,
                                          int row0, float Xs[][68], float Ws[][64]) {
    int tx = threadIdx.x & 15, ty = threadIdx.x >> 4;
    float acc[4][4] = {};
    for (int kb = 0; kb < K; kb += 64) {
        __syncthreads();
        // stage W chunk: 64 k x 64 out = 1024 float4, coalesced
        for (int i = threadIdx.x; i < 1024; i += 256) {
            int kk = i >> 4, c4 = i & 15;
            *(float4*)&Ws[kk][c4 * 4] = *(const float4*)&W[(kb + kk) * 64 + c4 * 4];
        }
        for (int i = threadIdx.x; i < 1024; i += 256) {  // 64 rows x 16 float4
            int r = i >> 4, k4 = i & 15;
            int gr = row0 + r; if (gr >= NN) gr = NN - 1;
            float4 v = *(const float4*)(X + (long long)gr * K + kb + k4 * 4);
            *(float4*)&Xs[r][k4 * 4] = v;
        }
        __syncthreads();
#pragma unroll
        for (int k4 = 0; k4 < 16; ++k4) {
            float4 w0 = *(const float4*)&Ws[k4 * 4 + 0][tx * 4];
            float4 w1 = *(const float4*)&Ws[k4 * 4 + 1][tx * 4];
            float4 w2 = *(const float4*)&Ws[k4 * 4 + 2][tx * 4];
            float4 w3 = *(const float4*)&Ws[k4 * 4 + 3][tx * 4];
            float4 x0 = *(const float4*)&Xs[ty * 4 + 0][k4 * 4];
            float4 x1 = *(const float4*)&Xs[ty * 4 + 1][k4 * 4];
            float4 x2 = *(const float4*)&Xs[ty * 4 + 2][k4 * 4];
            float4 x3 = *(const float4*)&Xs[ty * 4 + 3][k4 * 4];
#define GCN_ROW(j, xv) \
            acc[j][0]=fmaf(xv.x,w0.x,acc[j][0]); acc[j][1]=fmaf(xv.x,w0.y,acc[j][1]); \
            acc[j][2]=fmaf(xv.x,w0.z,acc[j][2]); acc[j][3]=fmaf(xv.x,w0.w,acc[j][3]); \
            acc[j][0]=fmaf(xv.y,w1.x,acc[j][0]); acc[j][1]=fmaf(xv.y,w1.y,acc[j][1]); \
            acc[j][2]=fmaf(xv.y,w1.z,acc[j][2]); acc[j][3]=fmaf(xv.y,w1.w,acc[j][3]); \
            acc[j][0]=fmaf(xv.z,w2.x,acc[j][0]); acc[j][1]=fmaf(xv.z,w2.y,acc[j][1]); \
            acc[j][2]=fmaf(xv.z,w2.z,acc[j][2]); acc[j][3]=fmaf(xv.z,w2.w,acc[j][3]); \
            acc[j][0]=fmaf(xv.w,w3.x,acc[j][0]); acc[j][1]=fmaf(xv.w,w3.y,acc[j][1]); \
            acc[j][2]=fmaf(xv.w,w3.z,acc[j][2]); acc[j][3]=fmaf(xv.w,w3.w,acc[j][3]);
            GCN_ROW(0, x0)
            GCN_ROW(1, x1)
            GCN_ROW(2, x2)
            GCN_ROW(3, x3)
#undef GCN_ROW
        }
    }
#pragma unroll
    for (int j = 0; j < 4; ++j) {
        int r = row0 + ty * 4 + j;
        if (r < NN) {
            ushort4 sv;
            sv.x = fbf(acc[j][0]); sv.y = fbf(acc[j][1]);
            sv.z = fbf(acc[j][2]); sv.w = fbf(acc[j][3]);
            *(ushort4*)(out + (long long)r * 64 + tx * 4) = sv;
        }
    }
}

// ---------------- fused: role-split hist blocks || gemm blocks -------------------------
__global__ __launch_bounds__(256) void hist_gemm_kernel(const int* __restrict__ dst,
                                                        const float* __restrict__ ew,
                                                        unsigned long long* __restrict__ h,
                                                        int* __restrict__ rank,
                                                        const float* __restrict__ X,
                                                        const float* __restrict__ W,
                                                        ushort* __restrict__ out) {
    __shared__ float Xs[64][68];      // 2-way conflicts only (free)
    __shared__ float Ws[64][64];      // K-chunk of W
    if (blockIdx.x < HB) {
        // one 64-bit atomic per edge: count in [40:64), sum(ew) fixed-point 2^-20 in [0:40)
        // returned old count = edge's rank within its dst group (free CSR fill counter)
        for (int e = blockIdx.x * 256 + threadIdx.x; e < NE; e += HB * 256) {
            int d = dst[e];
            unsigned int fx = __float2uint_rn(ew[e] * 1048576.0f);
            unsigned long long pack = (1ULL << 40) | (unsigned long long)fx;
            unsigned long long old = atomicAdd(&h[d], pack);
            rank[e] = (int)(old >> 40);
        }
        return;
    }
    gemm_body<128>(X, W, out, (blockIdx.x - HB) * 64, Xs, Ws);
}

// fused: dinv computation + per-block count reduction (scan phase A)
__global__ __launch_bounds__(256) void dinv_scanA_kernel(const unsigned long long* __restrict__ h,
                                                         float* __restrict__ dinv,
                                                         int* __restrict__ partial) {
    int i = blockIdx.x * 256 + threadIdx.x;
    int cnt = 0;
    if (i < NN) {
        unsigned long long v = h[i];
        cnt = (int)(v >> 40);
        float deg = (float)(v & ((1ULL << 40) - 1)) * (1.0f / 1048576.0f) + 1.0f;
        dinv[i] = 1.0f / sqrtf(deg);
    }
    __shared__ int wsum[4];
    int lane = threadIdx.x & 63, wid = threadIdx.x >> 6;
    int v = cnt;
#pragma unroll
    for (int off = 32; off > 0; off >>= 1) v += __shfl_down(v, (unsigned)off, 64);
    if (lane == 0) wsum[wid] = v;
    __syncthreads();
    if (threadIdx.x == 0) partial[blockIdx.x] = wsum[0] + wsum[1] + wsum[2] + wsum[3];
}

__device__ __forceinline__ int block_scan_inclusive(int v, int* wtot) {
    int lane = threadIdx.x & 63, wid = threadIdx.x >> 6;
    int inc = v;
#pragma unroll
    for (int off = 1; off < 64; off <<= 1) {
        int n = __shfl_up(inc, (unsigned)off, 64);
        if (lane >= off) inc += n;
    }
    if (lane == 63) wtot[wid] = inc;
    __syncthreads();
    int add = 0;
    for (int w = 0; w < wid; ++w) add += wtot[w];
    return inc + add;
}

// fused: per-block prefix of partials (196 L2-hot ints) + rowptr finalize + graph bounds
__global__ __launch_bounds__(256) void scanC_bounds_kernel(const unsigned long long* __restrict__ h,
                                                           const int* __restrict__ partial,
                                                           int* __restrict__ rowptr,
                                                           const int* __restrict__ batch,
                                                           int* __restrict__ gbeg,
                                                           int* __restrict__ gend) {
    __shared__ int wtot[4];
    __shared__ int poff_s;
    int t = threadIdx.x;
    if (t < 64) {   // wave 0: poff = sum partial[0..bid-1]
        int s = 0;
        for (int i = t; i < (int)blockIdx.x; i += 64) s += partial[i];
#pragma unroll
        for (int off = 32; off > 0; off >>= 1) s += __shfl_down(s, (unsigned)off, 64);
        if (t == 0) poff_s = s;
    }
    int i = blockIdx.x * 256 + t;
    int v = (i < NN) ? (int)(h[i] >> 40) : 0;
    int incl = block_scan_inclusive(v, wtot);   // internal __syncthreads makes poff_s visible
    if (i < NN) {
        rowptr[i + 1] = poff_s + incl;
        int g = batch[i];
        if (i == 0 || batch[i - 1] != g) gbeg[g] = i;
        if (i == NN - 1 || batch[i + 1] != g) gend[g] = i + 1;
    }
    if (i == 0) rowptr[0] = 0;
}

// Atomic-free scatter: pos = rowptr[d] + rank[e]; epack[pos] = (src, dinv[s]*ew)
__global__ __launch_bounds__(256) void scatter_kernel(const int* __restrict__ src,
                                                      const int* __restrict__ dst,
                                                      const float* __restrict__ ew,
                                                      const float* __restrict__ dinv,
                                                      const int* __restrict__ rowptr,
                                                      const int* __restrict__ rank,
                                                      int2* __restrict__ epack) {
    int e = blockIdx.x * blockDim.x + threadIdx.x;
    if (e >= NE) return;
    int s = src[e], d = dst[e];
    int pos = rowptr[d] + rank[e];
    float coef = dinv[s] * ew[e];
    epack[pos] = make_int2(s, __float_as_int(coef));
}

// ---------------- fused agg1 + ReLU + gemm2: per block, 16 nodes (4 per wave) ----------
// Phase 1 (per wave, t = 0..3): h1 row for node base+t -> h1s[w][t][:], fp32.
// Phase 2: AFTER all edge loops, load this thread's W2 column (outch = lane) into 64
// VGPRs — short live range, constant indices, so no spill (r9's spill came from w2c
// being live ACROSS the runtime edge loop) — then 4 nodes x {16 wave-uniform
// ds_read_b128 + 64 FMA}. W2 traffic amortized 4x vs r10 (64 -> 16 loads/node/wave).
__global__ __launch_bounds__(256) void agg_gemm_kernel(const ushort* __restrict__ xw,
                                                       const int* __restrict__ rowptr,
                                                       const int2* __restrict__ epack,
                                                       const float* __restrict__ dinv,
                                                       const float* __restrict__ bias,
                                                       const float* __restrict__ W2,
                                                       ushort* __restrict__ xw2) {
    __shared__ float h1s[4][4][64];    // [wave][node-slot][ch]
    int w = threadIdx.x >> 6;
    int lane = threadIdx.x & 63;
    int e8 = lane >> 3;      // edge slot 0..7
    int l8 = lane & 7;       // channel group: ch 8*l8 .. 8*l8+7
    int base = blockIdx.x * 16 + w * 4;      // 4 consecutive nodes for this wave
    for (int t = 0; t < 4; ++t) {
        int node = base + t;                 // always < NN (NN % 16 == 0)
        int beg = rowptr[node], end = rowptr[node + 1];
        float a0 = 0.f, a1 = 0.f, a2 = 0.f, a3 = 0.f;
        float a4 = 0.f, a5 = 0.f, a6 = 0.f, a7 = 0.f;
        for (int j = beg + e8; j < end; j += 8) {
            int2 p = epack[j];                                   // broadcast among 8 lanes
            uint4 v = *(const uint4*)(xw + p.x * 64 + l8 * 8);   // 16B = 8 bf16 channels
            float wt = __int_as_float(p.y);
            a0 = fmaf(wt, __uint_as_float(v.x << 16), a0);
            a1 = fmaf(wt, __uint_as_float(v.x & 0xffff0000u), a1);
            a2 = fmaf(wt, __uint_as_float(v.y << 16), a2);
            a3 = fmaf(wt, __uint_as_float(v.y & 0xffff0000u), a3);
            a4 = fmaf(wt, __uint_as_float(v.z << 16), a4);
            a5 = fmaf(wt, __uint_as_float(v.z & 0xffff0000u), a5);
            a6 = fmaf(wt, __uint_as_float(v.w << 16), a6);
            a7 = fmaf(wt, __uint_as_float(v.w & 0xffff0000u), a7);
        }
#define RED(x) x += __shfl_xor(x, 8); x += __shfl_xor(x, 16); x += __shfl_xor(x, 32);
        RED(a0) RED(a1) RED(a2) RED(a3) RED(a4) RED(a5) RED(a6) RED(a7)
#undef RED
        if (e8 == 0) {
            float di = dinv[node];
            float d2 = di * di;
            uint4 us = *(const uint4*)(xw + node * 64 + l8 * 8);
            float4 bv0 = *(const float4*)(bias + l8 * 8);
            float4 bv1 = *(const float4*)(bias + l8 * 8 + 4);
            float o0 = fmaf(di, a0, fmaf(d2, __uint_as_float(us.x << 16), bv0.x));
            float o1 = fmaf(di, a1, fmaf(d2, __uint_as_float(us.x & 0xffff0000u), bv0.y));
            float o2 = fmaf(di, a2, fmaf(d2, __uint_as_float(us.y << 16), bv0.z));
            float o3 = fmaf(di, a3, fmaf(d2, __uint_as_float(us.y & 0xffff0000u), bv0.w));
            float o4 = fmaf(di, a4, fmaf(d2, __uint_as_float(us.z << 16), bv1.x));
            float o5 = fmaf(di, a5, fmaf(d2, __uint_as_float(us.z & 0xffff0000u), bv1.y));
            float o6 = fmaf(di, a6, fmaf(d2, __uint_as_float(us.w << 16), bv1.z));
            float o7 = fmaf(di, a7, fmaf(d2, __uint_as_float(us.w & 0xffff0000u), bv1.w));
            *(float4*)&h1s[w][t][l8 * 8]     = make_float4(fmaxf(o0, 0.f), fmaxf(o1, 0.f),
                                                           fmaxf(o2, 0.f), fmaxf(o3, 0.f));
            *(float4*)&h1s[w][t][l8 * 8 + 4] = make_float4(fmaxf(o4, 0.f), fmaxf(o5, 0.f),
                                                           fmaxf(o6, 0.f), fmaxf(o7, 0.f));
        }
    }
    __syncthreads();
    // phase 2: this thread's W2 column (outch = lane) -> registers (coalesced per k);
    // live range starts here, all indices compile-time constant after unroll.
    float w2c[64];
#pragma unroll
    for (int k = 0; k < 64; ++k) w2c[k] = W2[k * 64 + lane];
#pragma unroll
    for (int t = 0; t < 4; ++t) {
        float acc = 0.f;      // k ascending: identical accumulation order (bitexact)
#pragma unroll
        for (int k4 = 0; k4 < 16; ++k4) {
            float4 hv = *(const float4*)&h1s[w][t][k4 * 4];   // wave-uniform b128 read
            acc = fmaf(hv.x, w2c[k4 * 4 + 0], acc);
            acc = fmaf(hv.y, w2c[k4 * 4 + 1], acc);
            acc = fmaf(hv.z, w2c[k4 * 4 + 2], acc);
            acc = fmaf(hv.w, w2c[k4 * 4 + 3], acc);
        }
        xw2[(base + t) * 64 + lane] = fbf(acc);
    }
}

// ---------------- CSR aggregation (layer 2): 8 lanes/edge x 8 ch/lane ------------------
template <bool RELU>
__global__ __launch_bounds__(256) void agg_kernel(const ushort* __restrict__ xw,
                                                  const int* __restrict__ rowptr,
                                                  const int2* __restrict__ epack,
                                                  const float* __restrict__ dinv,
                                                  const float* __restrict__ bias,
                                                  ushort* __restrict__ out) {
    int node = blockIdx.x * 4 + (threadIdx.x >> 6);
    int lane = threadIdx.x & 63;
    int e8 = lane >> 3;
    int l8 = lane & 7;
    int beg = rowptr[node], end = rowptr[node + 1];
    float a0 = 0.f, a1 = 0.f, a2 = 0.f, a3 = 0.f;
    float a4 = 0.f, a5 = 0.f, a6 = 0.f, a7 = 0.f;
    for (int j = beg + e8; j < end; j += 8) {
        int2 p = epack[j];
        uint4 v = *(const uint4*)(xw + p.x * 64 + l8 * 8);
        float w = __int_as_float(p.y);
        a0 = fmaf(w, __uint_as_float(v.x << 16), a0);
        a1 = fmaf(w, __uint_as_float(v.x & 0xffff0000u), a1);
        a2 = fmaf(w, __uint_as_float(v.y << 16), a2);
        a3 = fmaf(w, __uint_as_float(v.y & 0xffff0000u), a3);
        a4 = fmaf(w, __uint_as_float(v.z << 16), a4);
        a5 = fmaf(w, __uint_as_float(v.z & 0xffff0000u), a5);
        a6 = fmaf(w, __uint_as_float(v.w << 16), a6);
        a7 = fmaf(w, __uint_as_float(v.w & 0xffff0000u), a7);
    }
#define RED(x) x += __shfl_xor(x, 8); x += __shfl_xor(x, 16); x += __shfl_xor(x, 32);
    RED(a0) RED(a1) RED(a2) RED(a3) RED(a4) RED(a5) RED(a6) RED(a7)
#undef RED
    if (e8 == 0) {
        float di = dinv[node];
        float d2 = di * di;
        uint4 us = *(const uint4*)(xw + node * 64 + l8 * 8);
        float4 bv0 = *(const float4*)(bias + l8 * 8);
        float4 bv1 = *(const float4*)(bias + l8 * 8 + 4);
        float o0 = fmaf(di, a0, fmaf(d2, __uint_as_float(us.x << 16), bv0.x));
        float o1 = fmaf(di, a1, fmaf(d2, __uint_as_float(us.x & 0xffff0000u), bv0.y));
        float o2 = fmaf(di, a2, fmaf(d2, __uint_as_float(us.y << 16), bv0.z));
        float o3 = fmaf(di, a3, fmaf(d2, __uint_as_float(us.y & 0xffff0000u), bv0.w));
        float o4 = fmaf(di, a4, fmaf(d2, __uint_as_float(us.z << 16), bv1.x));
        float o5 = fmaf(di, a5, fmaf(d2, __uint_as_float(us.z & 0xffff0000u), bv1.y));
        float o6 = fmaf(di, a6, fmaf(d2, __uint_as_float(us.w << 16), bv1.z));
        float o7 = fmaf(di, a7, fmaf(d2, __uint_as_float(us.w & 0xffff0000u), bv1.w));
        if (RELU) {
            o0 = fmaxf(o0, 0.f); o1 = fmaxf(o1, 0.f); o2 = fmaxf(o2, 0.f); o3 = fmaxf(o3, 0.f);
            o4 = fmaxf(o4, 0.f); o5 = fmaxf(o5, 0.f); o6 = fmaxf(o6, 0.f); o7 = fmaxf(o7, 0.f);
        }
        uint4 sv;
        sv.x = (unsigned)fbf(o0) | ((unsigned)fbf(o1) << 16);
        sv.y = (unsigned)fbf(o2) | ((unsigned)fbf(o3) << 16);
        sv.z = (unsigned)fbf(o4) | ((unsigned)fbf(o5) << 16);
        sv.w = (unsigned)fbf(o6) | ((unsigned)fbf(o7) << 16);
        *(uint4*)(out + node * 64 + l8 * 8) = sv;
    }
}

// ---------------- fused mean-pool + MLP head: 4 waves per graph (h is bf16) -----------
__global__ __launch_bounds__(256) void poolhead_kernel(const ushort* __restrict__ h,
                                                       const int* __restrict__ gbeg,
                                                       const int* __restrict__ gend,
                                                       const float* __restrict__ LW1,
                                                       const float* __restrict__ Lb1,
                                                       const float* __restrict__ LW2,
                                                       const float* __restrict__ Lb2,
                                                       float* __restrict__ out) {
    __shared__ float pp[4][64];
    __shared__ float p[64];
    __shared__ float t1[32];
    int g = blockIdx.x, t = threadIdx.x;
    int lane = t & 63, wid = t >> 6;
    int b = gbeg[g], e = gend[g];
    float acc = 0.f;
    for (int i = b + wid; i < e; i += 4) acc += bfu(h[i * 64 + lane]);
    pp[wid][lane] = acc;
    __syncthreads();
    if (t < 64) {
        float s = pp[0][t] + pp[1][t] + pp[2][t] + pp[3][t];
        p[t] = s / fmaxf((float)(e - b), 1.0f);
    }
    __syncthreads();
    if (t < 32) {
        float a = Lb1[t];
#pragma unroll
        for (int k = 0; k < 64; ++k) a = fmaf(p[k], LW1[k * 32 + t], a);
        t1[t] = a;
    }
    __syncthreads();
    if (t < 10) {
        float a = Lb2[t];
#pragma unroll
        for (int j = 0; j < 32; ++j) a = fmaf(t1[j], LW2[j * 10 + t], a);
        out[g * 10 + t] = a;
    }
}

// ---------------- launch ----------------

extern "C" void kernel_launch(void* const* d_in, const int* in_sizes, int n_in,
                              void* d_out, int out_size, void* d_ws, size_t ws_size,
                              hipStream_t stream) {
    const float* x     = (const float*)d_in[0];
    const int*   ei    = (const int*)d_in[1];   // [2, NE]
    const float* ew    = (const float*)d_in[2];
    const int*   batch = (const int*)d_in[3];
    const float* W1    = (const float*)d_in[4];
    const float* b1    = (const float*)d_in[5];
    const float* W2    = (const float*)d_in[6];
    const float* b2    = (const float*)d_in[7];
    const float* LW1   = (const float*)d_in[8];
    const float* Lb1   = (const float*)d_in[9];
    const float* LW2   = (const float*)d_in[10];
    const float* Lb2   = (const float*)d_in[11];

    const int* src = ei;
    const int* dst = ei + NE;

    // workspace layout (4-byte units)
    float* ws = (float*)d_ws;
    unsigned long long* h64 = (unsigned long long*)ws;  // [NN] ull: 0 .. 100096
    int*   gbeg   = (int*)(ws + 100096);       // [NG] -> 100608
    int*   gend   = (int*)(ws + 100608);       // [NG] -> 101120  (zero range ends here)
    float* dinv   = ws + 101120;               // [NN]   -> 151168
    int*   rowptr = (int*)(ws + 151168);       // [NN+1] -> 201248 (padded)
    int*   partial= (int*)(ws + 201248);       // [NB]   -> 201504 (even -> int2-aligned)
    int2*  epack  = (int2*)(ws + 201504);      // [NE]   -> 1801504
    ushort* xwA   = (ushort*)(ws + 1801504);   // [NN*64] bf16: xw1; later reused as h2 -> 3401504
    ushort* xwB   = (ushort*)(ws + 3401504);   // [NN*64] bf16: xw2 -> 5001504
    int*   rank   = (int*)(ws + 5001504);      // [NE] -> 5801504
    ushort* h2    = xwA;                       // xw1 dead once agg_gemm completes
    // total 5801504 floats = 23.2 MB

    zero_kernel<<<(101120 + 255) / 256, 256, 0, stream>>>(ws, 101120);

    // role-split: blocks [0,HB) = atomic histogram (grid-stride), rest = x @ W1 GEMM
    hist_gemm_kernel<<<HB + GEMM_BLOCKS, 256, 0, stream>>>(dst, ew, h64, rank, x, W1, xwA);
    dinv_scanA_kernel<<<NB, 256, 0, stream>>>(h64, dinv, partial);
    scanC_bounds_kernel<<<NB, 256, 0, stream>>>(h64, partial, rowptr, batch, gbeg, gend);
    scatter_kernel<<<(NE + 255) / 256, 256, 0, stream>>>(src, dst, ew, dinv, rowptr,
                                                         rank, epack);

    // ---- layer 1 aggregation + ReLU + layer-2 GEMM fused (16 nodes/block) ----
    agg_gemm_kernel<<<NN / 16, 256, 0, stream>>>(xwA, rowptr, epack, dinv, b1, W2, xwB);

    // ---- layer 2 aggregation ----
    agg_kernel<false><<<NN / 4, 256, 0, stream>>>(xwB, rowptr, epack, dinv, b2, h2);

    // ---- pool + head ----
    poolhead_kernel<<<NG, 256, 0, stream>>>(h2, gbeg, gend, LW1, Lb1, LW2, Lb2, (float*)d_out);
}